// Round 8
// baseline (2447.962 us; speedup 1.0000x reference)
//
#include <hip/hip_runtime.h>

// ---------------------------------------------------------------------------
// BlockLSTM forward, MI355X (gfx950).  T=512, B=64, I=U=512.
// out = [h_seq (T,B,U) | final_cs (B,U) | final_h (B,U)] fp32
//
// z-columns permuted unit-major: col' = u*4 + g  (orig col = g*512 + u).
// zxp stored in MFMA 32x32 C-fragment order (unchanged gemm epilogue).
//
// hbf layout (NEW, row-grouped): [t][grp(8)][kf(16)][quadc(4)][r8(8)][8u PERM]
//   elem = t*32768 + grp*4096 + kf*256 + quadc*64 + r8*8 + idx
//   group grp owns batch rows [grp*8, +8); chunk (kf,quadc) = producer cb
//   holds units [cb*8,+8) in perm order [0,4,1,5,2,6,3,7] (wT k>=512 perm'd
//   identically). Same 64KB/slot as before.
//
// SYNC: data-is-flag (bf16 NaN 0x7FC0 poison; h = tanh*sigmoid never NaN);
// speculative MFMA + NaN-validate on the accumulator (R4, proven 1053us).
//
// NEW (this version): XCD-LOCAL ROW-CLIQUES WITH RUNTIME PLACEMENT.
// R7 proved the step time is pinned by the MALL store->visibility->load
// chain (~2us), invariant to consumer structure (FETCH fell, time didn't).
// Rows are independent, so each 8-row group's 64-wave clique communicates
// only within itself. Blocks read the physical XCD id (s_getreg XCC_ID) and
// claim work from per-XCD queues (1024 blocks oversubscribe 512 slots,
// scanning all queues -> coverage guaranteed regardless of placement; G16:
// placement affects only speed). Native waves (group == own XCD) exchange h
// through the XCD's L2 via sc0 loads; fallback to agent (MALL) loads after
// 8 failed tries per step (sticky after 16 straight steps). Producers issue
// one agent-scope 4B store (write-through: local L2 updated for natives,
// MALL for orphans).
//
// MFMA orientation (R4): z^T = wT x h; D lane l15 = batch row (only 8 valid,
// lanes 8..15 duplicate rows), acc regs = 4 gates of one unit.
//
// ws layout (~164.1 MB):
//   [0,   4MB)        wT   bf16 [2048 permuted cols][1024 k (k>=512 perm)]
//   [4MB, 132MB)      zxp  bf16 [512][64][2][64][16]
//   [132MB, +32.06MB) hbf  bf16 [513 slots][32768]
//   [hbf end, +2KB)   qcnt u32 [8 XCD queues][64-pad]
// ---------------------------------------------------------------------------

#define T_STEPS 512
#define NB 64
#define NU 512
#define NI 512
#define KTOT 1024
#define ZCOLS 2048
#define HSEQ_ELEMS (T_STEPS * NB * NU)
#define POISON64 0x7FC07FC07FC07FC0ull

typedef float    floatx4   __attribute__((ext_vector_type(4)));
typedef __bf16   bf16x8    __attribute__((ext_vector_type(8)));
typedef unsigned short ushortx8 __attribute__((ext_vector_type(8)));
typedef unsigned long long ull_t;

static __device__ __forceinline__ unsigned short f2bf(float f) {
  unsigned int u = __builtin_bit_cast(unsigned int, f);
  u += 0x7fffu + ((u >> 16) & 1u);  // RNE
  return (unsigned short)(u >> 16);
}
static __device__ __forceinline__ float bf2f(unsigned short h) {
  unsigned int u = ((unsigned int)h) << 16;
  return __builtin_bit_cast(float, u);
}
static __device__ __forceinline__ float sigmoidf_(float x) {
  return __builtin_amdgcn_rcpf(1.0f + __expf(-x));
}
static __device__ __forceinline__ float fast_tanhf(float x) {
  const float ax = fabsf(x);
  const float t = __expf(-2.0f * ax);
  const float r = (1.0f - t) * __builtin_amdgcn_rcpf(1.0f + t);
  return copysignf(r, x);
}
static __device__ __forceinline__ bf16x8 ldfrag(const unsigned short* p) {
  ushortx8 v = *reinterpret_cast<const ushortx8*>(p);
  return __builtin_bit_cast(bf16x8, v);
}
static __device__ __forceinline__ ull_t pack4bf(float a, float b, float c, float d) {
  return (ull_t)f2bf(a) | ((ull_t)f2bf(b) << 16) | ((ull_t)f2bf(c) << 32) |
         ((ull_t)f2bf(d) << 48);
}

// ---------------------------------------------------------------------------
// init: poison hbf slots 1..512; slot0 = bf16(h0) in row-grouped frag layout;
// zero the per-XCD claim queues. grid 2056 x 256.
// ---------------------------------------------------------------------------
__global__ __launch_bounds__(256) void init_kernel(const float* __restrict__ h0,
                                                   unsigned short* __restrict__ hbf,
                                                   unsigned int* __restrict__ qcnt) {
  if (blockIdx.x == 0 && threadIdx.x < 8) qcnt[threadIdx.x * 64] = 0;
  const int j = blockIdx.x * 256 + threadIdx.x;  // 0..526335
  if (j < 524288) {
    ull_t* p = reinterpret_cast<ull_t*>(&hbf[32768 + (size_t)j * 32]);
#pragma unroll
    for (int r = 0; r < 8; ++r) p[r] = POISON64;
  } else {
    const int k = j - 524288;  // 0..2047
#pragma unroll
    for (int p2 = 0; p2 < 2; ++p2) {
      const int i = k * 2 + p2;  // 0..4095
      const int row = i >> 6, cb = i & 63;
      const float* src = &h0[row * NU + cb * 8];
      // perm [0,4,1,5,2,6,3,7]
      const ull_t lo = pack4bf(src[0], src[4], src[1], src[5]);
      const ull_t hi = pack4bf(src[2], src[6], src[3], src[7]);
      const size_t off = (size_t)(row >> 3) * 4096 + (size_t)(cb >> 2) * 256 +
                         (size_t)(cb & 3) * 64 + (size_t)(row & 7) * 8;
      *reinterpret_cast<ull_t*>(&hbf[off]) = lo;
      *reinterpret_cast<ull_t*>(&hbf[off + 4]) = hi;
    }
  }
}

// ---------------------------------------------------------------------------
// transpose + permute: wT[(u*4+g)][k'] = bf16(w[k][g*512+u]);
// k' = k for k<512, intra-8 permuted for k>=512 (matches hbf frag order).
// ---------------------------------------------------------------------------
__global__ __launch_bounds__(256) void transpose_w_kernel(
    const float* __restrict__ w, unsigned short* __restrict__ wT) {
  __shared__ float tile[32][33];
  const int u0 = blockIdx.x * 32;
  const int k0 = blockIdx.y * 32;
  const int g = blockIdx.z;
  const int tx = threadIdx.x & 31, ty = threadIdx.x >> 5;
#pragma unroll
  for (int r = 0; r < 4; ++r) {
    const int k = ty + r * 8;
    tile[k][tx] = w[(size_t)(k0 + k) * ZCOLS + g * 512 + u0 + tx];
  }
  __syncthreads();
#pragma unroll
  for (int r = 0; r < 4; ++r) {
    const int u = ty + r * 8;
    const int kk = k0 + tx;
    int kd = kk;
    if (kk >= 512) {
      const int u3 = kk & 7;
      kd = (kk & ~7) | (((u3 & 3) << 1) | (u3 >> 2));
    }
    wT[(size_t)((u0 + u) * 4 + g) * KTOT + kd] = f2bf(tile[tx][u]);
  }
}

// ---------------------------------------------------------------------------
// gemm: zxp = (x @ wx + b) in permuted cols, 32x32 C-fragment order.
// ---------------------------------------------------------------------------
__global__ __launch_bounds__(256) void gemm_zx_kernel(
    const float* __restrict__ x, const unsigned short* __restrict__ wT,
    const float* __restrict__ bias, unsigned short* __restrict__ zxp) {
  __shared__ __align__(16) unsigned short As[128][32];
  __shared__ __align__(16) unsigned short Bs[128][32];
  const int m0 = blockIdx.y * 128;
  const int n0 = blockIdx.x * 128;
  const int tid = threadIdx.x;
  const int wid = tid >> 6, lane = tid & 63;
  const int quad = lane >> 4, nl = lane & 15;
  const int wm = (wid & 1) * 64, wn = (wid >> 1) * 64;
  const int srow = tid >> 3;
  const int skk = (tid & 7) * 4;

  floatx4 acc[4][4] = {};

  for (int kt = 0; kt < 16; ++kt) {
    const int k0 = kt * 32;
    __syncthreads();
#pragma unroll
    for (int r = 0; r < 4; ++r) {
      const int row = r * 32 + srow;
      const float4 v =
          *reinterpret_cast<const float4*>(&x[(size_t)(m0 + row) * NI + k0 + skk]);
      *reinterpret_cast<ull_t*>(&As[row][skk]) = pack4bf(v.x, v.y, v.z, v.w);
      *reinterpret_cast<ull_t*>(&Bs[row][skk]) =
          *reinterpret_cast<const ull_t*>(&wT[(size_t)(n0 + row) * KTOT + k0 + skk]);
    }
    __syncthreads();
    bf16x8 af[4], bfr[4];
#pragma unroll
    for (int i = 0; i < 4; ++i) {
      af[i] = ldfrag(&As[wm + i * 16 + nl][quad * 8]);
      bfr[i] = ldfrag(&Bs[wn + i * 16 + nl][quad * 8]);
    }
#pragma unroll
    for (int i = 0; i < 4; ++i)
#pragma unroll
      for (int j = 0; j < 4; ++j)
        acc[i][j] =
            __builtin_amdgcn_mfma_f32_16x16x32_bf16(af[i], bfr[j], acc[i][j], 0, 0, 0);
  }

  float bv[4];
#pragma unroll
  for (int j = 0; j < 4; ++j) {
    const int colp = n0 + wn + j * 16 + nl;
    bv[j] = bias[(colp & 3) * 512 + (colp >> 2)];
  }
#pragma unroll
  for (int i = 0; i < 4; ++i) {
    const int browb = wm + i * 16 + quad * 4;
    const int t = (m0 + browb) >> 6;
    const int rt = (browb >> 5) & 1;
    const int hi = (browb & 31) >> 3;
    const int qb = (browb >> 2) & 1;
#pragma unroll
    for (int j = 0; j < 4; ++j) {
      const int colp = n0 + wn + j * 16 + nl;
      const int cbl = colp >> 5;
      const int lanep = (colp & 31) + 32 * qb;
      const ull_t packed =
          pack4bf(acc[i][j][0] + bv[j], acc[i][j][1] + bv[j],
                  acc[i][j][2] + bv[j], acc[i][j][3] + bv[j]);
      *reinterpret_cast<ull_t*>(
          &zxp[((((size_t)t * 64 + cbl) * 2 + rt) * 64 + lanep) * 16 + hi * 4]) = packed;
    }
  }
}

// ---------------------------------------------------------------------------
// recurrence: 1024 blocks x 64 thr; 512 claim work (grp = XCD-pref queue,
// cb = slot), rest exit. Native waves: sc0 (L2) h-loads; orphans/fallback:
// agent (MALL). Speculative MFMA + NaN-validate.
// ---------------------------------------------------------------------------
__global__ __launch_bounds__(64) void lstm_rec_kernel(
    const unsigned short* __restrict__ zxp, const unsigned short* __restrict__ wT,
    const float* __restrict__ cs_init, float* __restrict__ out,
    unsigned short* __restrict__ hbf, unsigned int* __restrict__ qcnt) {
  const int lane = threadIdx.x;

  // ---- runtime placement-aware work claim ----
  unsigned xcd;
  asm volatile("s_getreg_b32 %0, hwreg(HW_REG_XCC_ID)" : "=s"(xcd));
  xcd &= 7;
  int g = -1, cb = -1;
  bool native = false;
  for (int q = 0; q < 8; ++q) {
    const int qq = (int)((xcd + q) & 7);
    int s = 0;
    if (lane == 0) s = (int)atomicAdd(&qcnt[qq * 64], 1u);
    s = __shfl(s, 0);
    if (s < 64) { g = qq; cb = s; native = (q == 0); break; }
  }
  if (g < 0) return;  // all 512 slots claimed by other blocks

  const int l15 = lane & 15, quad = lane >> 4;
  const int r8 = l15 & 7;
  const int row = g * 8 + r8;            // lanes l15>=8 duplicate rows

  // A-operand resident: wT frags; lane m = l15 -> z-col cb*32 + cf*16 + l15
  bf16x8 Wf[2][16];
#pragma unroll
  for (int cf = 0; cf < 2; ++cf)
#pragma unroll
    for (int kf = 0; kf < 16; ++kf)
      Wf[cf][kf] = ldfrag(
          &wT[(size_t)(cb * 32 + cf * 16 + l15) * KTOT + 512 + kf * 32 + quad * 8]);

  // cell state: (row, units cb*8+quad and cb*8+4+quad)
  float csv[2];
  csv[0] = cs_init[row * NU + cb * 8 + quad];
  csv[1] = cs_init[row * NU + cb * 8 + 4 + quad];

  // h fragment state: 16 x 16B asm loads (manual vmcnt)
  floatx4 Af[16];
  auto issueA = [&](int tt, bool ag) {
    const unsigned short* p0 =
        hbf + (size_t)tt * 32768 + (size_t)g * 4096 + quad * 64 + r8 * 8;
    if (ag) {
#pragma unroll
      for (int kf = 0; kf < 16; ++kf)
        asm volatile("global_load_dwordx4 %0, %1, off sc0 sc1"
                     : "=v"(Af[kf]) : "v"(p0 + (size_t)kf * 256) : "memory");
    } else {
#pragma unroll
      for (int kf = 0; kf < 16; ++kf)
        asm volatile("global_load_dwordx4 %0, %1, off sc0"
                     : "=v"(Af[kf]) : "v"(p0 + (size_t)kf * 256) : "memory");
    }
  };

  // zx scalar preloads (gemm C-fragment layout), double-buffered
  const int rt_ = row >> 5;
  const int qb_ = (row >> 2) & 1;
  const int hi_ = (row & 31) >> 3;
  const int rr_ = row & 3;
  auto issueZ = [&](int tt, unsigned short (&zb)[8]) {
    const size_t base = (((size_t)tt * 64 + cb) * 2 + rt_) * 64;
#pragma unroll
    for (int cf = 0; cf < 2; ++cf)
#pragma unroll
      for (int gg = 0; gg < 4; ++gg) {
        const int c5 = cf * 16 + quad * 4 + gg;
        zb[cf * 4 + gg] = zxp[(base + (size_t)(c5 + 32 * qb_)) * 16 + hi_ * 4 + rr_];
      }
  };

  unsigned short zA[8], zB[8];
  bool agent = !native;
  int astreak = 0;

  issueA(0, agent);
  issueZ(0, zA);
  asm volatile("" ::: "memory");

  auto step = [&](int t, unsigned short (&zrd)[8], unsigned short (&zwr)[8]) {
    // ---- validate pre-issued frags: vmcnt(0) + spec-MFMA + NaN check ----
    floatx4 z0, z1;
    int tries = 0;
    bool sa = agent;
    for (;;) {
      asm volatile("s_waitcnt vmcnt(0)" ::: "memory");
      __builtin_amdgcn_sched_barrier(0);
      floatx4 p00 = {0.f, 0.f, 0.f, 0.f}, p01 = {0.f, 0.f, 0.f, 0.f};
      floatx4 p10 = {0.f, 0.f, 0.f, 0.f}, p11 = {0.f, 0.f, 0.f, 0.f};
#pragma unroll
      for (int kf = 0; kf < 8; ++kf) {
        const bf16x8 hlo = __builtin_bit_cast(bf16x8, Af[kf]);
        const bf16x8 hhi = __builtin_bit_cast(bf16x8, Af[8 + kf]);
        p00 = __builtin_amdgcn_mfma_f32_16x16x32_bf16(Wf[0][kf], hlo, p00, 0, 0, 0);
        p01 = __builtin_amdgcn_mfma_f32_16x16x32_bf16(Wf[1][kf], hlo, p01, 0, 0, 0);
        p10 = __builtin_amdgcn_mfma_f32_16x16x32_bf16(Wf[0][8 + kf], hhi, p10, 0, 0, 0);
        p11 = __builtin_amdgcn_mfma_f32_16x16x32_bf16(Wf[1][8 + kf], hhi, p11, 0, 0, 0);
      }
      z0 = p00 + p10;  // unit cb*8+quad   : gates (i,ci,f,o)
      z1 = p01 + p11;  // unit cb*8+4+quad : gates (i,ci,f,o)
      const float s = ((z0[0] + z0[1]) + (z0[2] + z0[3])) +
                      ((z1[0] + z1[1]) + (z1[2] + z1[3]));
      if (!__any(s != s) || ++tries >= (1 << 16)) break;
      if (!sa && tries >= 8) sa = true;  // local L2 path stale -> MALL
      issueA(t, sa);
    }
    if (!agent) {  // sticky fallback if the local path chronically fails
      if (sa) { if (++astreak >= 16) agent = true; }
      else astreak = 0;
    }

    // ---- zx for t+1 issued EARLY (retire long before next vmcnt(0)) ----
    if (t + 1 < T_STEPS) issueZ(t + 1, zwr);
    asm volatile("" ::: "memory");

    // ---- gates directly on acc regs + zx scalars ----
    float hout[2];
    {
      const float iv = sigmoidf_(z0[0] + bf2f(zrd[0]));
      const float civ = fast_tanhf(z0[1] + bf2f(zrd[1]));
      const float fv = sigmoidf_(z0[2] + bf2f(zrd[2]) + 1.0f);  // forget_bias
      const float ov = sigmoidf_(z0[3] + bf2f(zrd[3]));
      csv[0] = civ * iv + csv[0] * fv;
      hout[0] = fast_tanhf(csv[0]) * ov;
    }
    {
      const float iv = sigmoidf_(z1[0] + bf2f(zrd[4]));
      const float civ = fast_tanhf(z1[1] + bf2f(zrd[5]));
      const float fv = sigmoidf_(z1[2] + bf2f(zrd[6]) + 1.0f);
      const float ov = sigmoidf_(z1[3] + bf2f(zrd[7]));
      csv[1] = civ * iv + csv[1] * fv;
      hout[1] = fast_tanhf(csv[1]) * ov;
    }

    // ---- h store FIRST (R6 lesson): one 4B agent store, lanes l15<8 ----
    const unsigned hv = (unsigned)f2bf(hout[0]) | ((unsigned)f2bf(hout[1]) << 16);
    if (l15 < 8) {
      unsigned short* hw = &hbf[(size_t)(t + 1) * 32768 + (size_t)g * 4096 +
                                (size_t)(cb >> 2) * 256 + (size_t)(cb & 3) * 64 +
                                (size_t)r8 * 8 + 2 * quad];
      __hip_atomic_store(reinterpret_cast<unsigned*>(hw), hv, __ATOMIC_RELAXED,
                         __HIP_MEMORY_SCOPE_AGENT);
    }
    asm volatile("" ::: "memory");

    // ---- out stores (L2-absorbed acks) ----
    if (l15 < 8) {
      float* op = &out[((size_t)t * NB + row) * NU + cb * 8];
      op[quad] = hout[0];
      op[4 + quad] = hout[1];
      if (t == T_STEPS - 1) {
        float* cp = &out[HSEQ_ELEMS + (size_t)row * NU + cb * 8];
        cp[quad] = csv[0];
        cp[4 + quad] = csv[1];
        float* hp2 = &out[HSEQ_ELEMS + NB * NU + (size_t)row * NU + cb * 8];
        hp2[quad] = hout[0];
        hp2[4 + quad] = hout[1];
      }
    }
    asm volatile("" ::: "memory");

    // ---- pre-issue next step's h loads LAST (youngest vm ops) ----
    if (t + 1 < T_STEPS) issueA(t + 1, agent);
  };

  for (int t = 0; t < T_STEPS; t += 2) {
    step(t, zA, zB);
    step(t + 1, zB, zA);
  }
}

// ---------------------------------------------------------------------------
extern "C" void kernel_launch(void* const* d_in, const int* in_sizes, int n_in,
                              void* d_out, int out_size, void* d_ws, size_t ws_size,
                              hipStream_t stream) {
  const float* x = (const float*)d_in[0];
  const float* cs0 = (const float*)d_in[1];
  const float* h0 = (const float*)d_in[2];
  const float* w = (const float*)d_in[3];
  const float* bias = (const float*)d_in[4];
  float* out = (float*)d_out;

  char* ws = (char*)d_ws;
  unsigned short* wT = (unsigned short*)(ws);
  unsigned short* zxp = (unsigned short*)(ws + (size_t)(4 << 20));
  unsigned short* hbf = (unsigned short*)(ws + (size_t)(132 << 20));
  unsigned int* qcnt = (unsigned int*)(ws + (size_t)(164 << 20) + (1 << 16));

  init_kernel<<<dim3(2056), 256, 0, stream>>>(h0, hbf, qcnt);
  transpose_w_kernel<<<dim3(16, 32, 4), 256, 0, stream>>>(w, wT);
  gemm_zx_kernel<<<dim3(16, 256), 256, 0, stream>>>(x, wT, bias, zxp);
  lstm_rec_kernel<<<dim3(1024), 64, 0, stream>>>(zxp, wT, cs0, out, hbf, qcnt);
}